// Round 6
// baseline (190.013 us; speedup 1.0000x reference)
//
#include <hip/hip_runtime.h>

// Gather + ragged segment XOR reduction.
// History:
//  R1/R2: direct gather 142 us — L2-miss line-fill bound (table >> 4 MB/XCD L2).
//  R4: slice-bucket + XCD-pinned gather; gather ~60, bucket 67 (occupancy).
//  R5: global-atomic bucketizer regressed (139 MB scattered writes). Reverted.
//  R6: LDS-staged ordered scatter + binary-search labels: bucket ~30, gather
//    61.4, total 189 us (best).
//  R7: padded 32B rows: gather flat (confounded: 32 MB table -> L2 thrash).
//  R8: ballot-aggregated bucket atomics: 30->96 us (VALU-bound). Reverted.
//  R9: 64-bit LDS atomicXor: memory-backed path on gfx950. NEVER use. Reverted.
//  R10: 2-way unrolled gather loop: FLAT => not latency-bound.
//  R12: split e4[int4]+e1[int]: gather 60->90. lines/token 1.125->2.0 =>
//    REGRESSED => gather is L1 LINE-FILL-RATE bound.
//  R13: pack-3 rows/64B line: gather 52.0 (fills/token -> 1.0). Fit:
//    cyc/token = 0.2*lane_reqs + 2.8*fills + ~0.6 DS.
//  R14: nontemporal row loads: gather 120, FETCH 29.7->52.9 MB. HW FACT: nt on
//    gfx950 is evict-first in L2 TOO. NEVER nt-load L2-pinned data. Reverted.
//  R15: sc0 row loads (L1-bypass, L2-normal): gather FLAT 52, FETCH restored.
//    => the ~2.8cyc/line is the miss-processing/TA path, NOT L1 allocate.
//    Gather is at ~75-80% of its structural pipe. Accepted.
//  R16 (this): bucket-side. Replace per-token 7-step binary search with
//    wave-parallel hint-label fill into stage[] (boundaries are known from
//    lstart; O(T) total), pass-1 ORs idx in. Expect bucket -5..8 us.

#define HPG        128     // hints per group
#define NSL        16      // slices (idx>>16), N <= 2^20
#define STAGE_CAP  12288   // tokens staged in LDS; mean 8192, +10 sigma

typedef int iv4 __attribute__((ext_vector_type(4), aligned(4)));

__device__ __forceinline__ int clip_idx(int v, int N) {
    return min(max(v, 0), N - 1);
}

// ---------------- Kernel A: bucketize (one group per block) + pack-3 repack ----------------
__global__ __launch_bounds__(1024) void bucket_kernel(
    const int* __restrict__ blocks,
    const int* __restrict__ offsets,
    const int* __restrict__ starts,
    const int* __restrict__ bs_ptr,
    const int* __restrict__ entries,     // overflow path + repack source
    int* __restrict__ out,               // zeroed here; overflow path
    unsigned int* __restrict__ buck,     // [T] u32: idx(20) | localHint(<<20)
    unsigned int* __restrict__ tab,      // [NG*NSL*2] {absBase, count}
    int* __restrict__ ep,                // packed table: 3 rows / 64B (may be null)
    int H, int N, int T)
{
    __shared__ unsigned int stage[STAGE_CAP];
    __shared__ int lstart[HPG + 1];
    __shared__ unsigned int cnt[NSL], off[NSL], lcur[NSL];

    const int g  = blockIdx.x;
    const int t  = threadIdx.x;

    // Pack-3 repack: row r -> ep + (r/3)*16 + (r%3)*5. 64B-aligned blocks,
    // rows at byte offsets {0,20,40}: no row crosses a 64B (or 128B) line.
    if (ep) {
        for (int r = blockIdx.x * 1024 + t; r < N; r += gridDim.x * 1024) {
            const int* row = entries + (long)r * 5;
            const unsigned int q = (unsigned int)r / 3u;
            const unsigned int m = (unsigned int)r - q * 3u;
            int* dst = ep + (size_t)q * 16 + m * 5;
            dst[0] = row[0]; dst[1] = row[1]; dst[2] = row[2];
            dst[3] = row[3]; dst[4] = row[4];
        }
    }

    const int h0 = g * HPG;
    const int h1 = min(H, h0 + HPG);
    const int nh = h1 - h0;
    const int bs = bs_ptr[0];

    // Zero this group's slice of out (replaces the separate memset dispatch).
    {
        int* oz = out + (long)h0 * 5;
        const int zn = nh * 5;
        for (int i = t; i < zn; i += 1024) oz[i] = 0;
    }

    if (t < nh) lstart[t] = starts[h0 + t];
    if (t == 0) lstart[nh] = (h1 < H) ? starts[h1] : T;
    if (t < NSL) { cnt[t] = 0; lcur[t] = 0; }
    __syncthreads();

    const int tokBase = lstart[0];
    const int count   = lstart[nh] - tokBase;
    const int staged  = min(count, STAGE_CAP);

    // phase 0: wave-parallel hint-label fill. Wave w handles hints
    // h = w, w+16, ...: lanes write (h<<20) across the hint's token span.
    // Replaces the per-token binary search (7 dependent LDS reads) of R6.
    {
        const int wave = t >> 6;
        const int lane = t & 63;
        for (int h = wave; h < nh; h += 16) {
            const int s0 = lstart[h]     - tokBase;
            const int s1 = min(lstart[h + 1] - tokBase, staged);
            const unsigned int lab = (unsigned int)h << 20;
            for (int i = s0 + lane; i < s1; i += 64) stage[i] = lab;
        }
    }
    __syncthreads();

    // pass 1: idx -> OR into labelled stage; per-slice histogram
    for (int i = t; i < staged; i += 1024) {
        const int gpos = tokBase + i;
        const int idx  = clip_idx(blocks[gpos] * bs + offsets[gpos], N);
        stage[i] |= (unsigned int)idx;
        atomicAdd(&cnt[(unsigned int)idx >> 16], 1u);
    }
    __syncthreads();

    // exclusive prefix over 16 slice counts
    if (t == 0) {
        unsigned int run = 0;
        for (int s = 0; s < NSL; ++s) { off[s] = run; run += cnt[s]; }
    }
    __syncthreads();

    if (t < NSL) {
        tab[(g * NSL + t) * 2 + 0] = (unsigned int)tokBase + off[t];
        tab[(g * NSL + t) * 2 + 1] = cnt[t];
    }

    // pass 2: ordered scatter into the group's own CSR range
    for (int i = t; i < staged; i += 1024) {
        const unsigned int w = stage[i];
        const unsigned int s = (w >> 16) & (NSL - 1);
        const unsigned int r = atomicAdd(&lcur[s], 1u);
        buck[(unsigned int)tokBase + off[s] + r] = w;
    }

    // overflow remainder (count > STAGE_CAP): statistically never; correctness.
    // Keeps the binary search (cold path).
    for (int i = staged + t; i < count; i += 1024) {
        const int gpos = tokBase + i;
        const int idx  = clip_idx(blocks[gpos] * bs + offsets[gpos], N);
        int lo = 0, hi = nh - 1;
        while (lo < hi) {
            int m = (lo + hi + 1) >> 1;
            if (lstart[m] <= gpos) lo = m; else hi = m - 1;
        }
        const int* row = entries + (long)idx * 5;
        int* o5 = out + (long)(h0 + lo) * 5;
        atomicXor(&o5[0], row[0]); atomicXor(&o5[1], row[1]);
        atomicXor(&o5[2], row[2]); atomicXor(&o5[3], row[3]);
        atomicXor(&o5[4], row[4]);
    }
}

// ---------------- Kernel B (packed): XCD-pinned gather + LDS accumulate ----------------
// Grid = 2048 (resident capacity) so blockIdx&7 -> XCD round-robin holds.
// Block (x,g) touches only slices {x, x+8} -> ~2.9 MB packed rows, L2-resident.
// Per token: ONE line; rows read with sc0 (L1-bypass, L2-normal).
__global__ __launch_bounds__(256) void gather_kernel_packed(
    const unsigned int* __restrict__ buck,
    const unsigned int* __restrict__ tab,
    const int* __restrict__ ep,
    int* __restrict__ out,
    int H, int NG, int nSl, int groupsPerBlock)
{
    __shared__ int acc[HPG * 5];

    const int B = blockIdx.x;
    const int x = B & 7;
    const int g0 = B >> 3;
    const int t = threadIdx.x;
    const int gStride = gridDim.x >> 3;

    for (int k = 0; k < groupsPerBlock; ++k) {
        const int g = g0 + k * gStride;
        if (g >= NG) break;

        for (int i = t; i < HPG * 5; i += 256) acc[i] = 0;
        __syncthreads();

        for (int s = x; s < nSl; s += 8) {
            const unsigned int base = tab[(g * NSL + s) * 2 + 0];
            const unsigned int cn   = tab[(g * NSL + s) * 2 + 1];

            unsigned int i = t;
            for (; i + 256 < cn; i += 512) {
                const unsigned int w0 = buck[base + i];
                const unsigned int w1 = buck[base + i + 256];
                const unsigned int idx0 = w0 & 0xFFFFFu;
                const unsigned int idx1 = w1 & 0xFFFFFu;
                const int h0 = (int)(w0 >> 20);
                const int h1 = (int)(w1 >> 20);
                const unsigned int q0 = idx0 / 3u, m0 = idx0 - q0 * 3u;
                const unsigned int q1 = idx1 / 3u, m1 = idx1 - q1 * 3u;
                const int* r0 = ep + (size_t)q0 * 16 + m0 * 5;
                const int* r1 = ep + (size_t)q1 * 16 + m1 * 5;
                // sc0: bypass L1 allocate, normal L2 caching. One address
                // per row; col4 via offset:16 from the same line.
                iv4 a, b; int a4, b4;
                asm volatile(
                    "global_load_dwordx4 %0, %4, off sc0\n\t"
                    "global_load_dword   %1, %4, off offset:16 sc0\n\t"
                    "global_load_dwordx4 %2, %5, off sc0\n\t"
                    "global_load_dword   %3, %5, off offset:16 sc0\n\t"
                    "s_waitcnt vmcnt(0)"
                    : "=&v"(a), "=&v"(a4), "=&v"(b), "=&v"(b4)
                    : "v"(r0), "v"(r1)
                    : "memory");
                atomicXor(&acc[h0 * 5 + 0], a.x);
                atomicXor(&acc[h0 * 5 + 1], a.y);
                atomicXor(&acc[h0 * 5 + 2], a.z);
                atomicXor(&acc[h0 * 5 + 3], a.w);
                atomicXor(&acc[h0 * 5 + 4], a4);
                atomicXor(&acc[h1 * 5 + 0], b.x);
                atomicXor(&acc[h1 * 5 + 1], b.y);
                atomicXor(&acc[h1 * 5 + 2], b.z);
                atomicXor(&acc[h1 * 5 + 3], b.w);
                atomicXor(&acc[h1 * 5 + 4], b4);
            }
            if (i < cn) {
                const unsigned int w = buck[base + i];
                const unsigned int idx = w & 0xFFFFFu;
                const int h = (int)(w >> 20);
                const unsigned int q = idx / 3u, m = idx - q * 3u;
                const int* r0 = ep + (size_t)q * 16 + m * 5;
                iv4 a; int a4;
                asm volatile(
                    "global_load_dwordx4 %0, %2, off sc0\n\t"
                    "global_load_dword   %1, %2, off offset:16 sc0\n\t"
                    "s_waitcnt vmcnt(0)"
                    : "=&v"(a), "=&v"(a4)
                    : "v"(r0)
                    : "memory");
                atomicXor(&acc[h * 5 + 0], a.x);
                atomicXor(&acc[h * 5 + 1], a.y);
                atomicXor(&acc[h * 5 + 2], a.z);
                atomicXor(&acc[h * 5 + 3], a.w);
                atomicXor(&acc[h * 5 + 4], a4);
            }
        }
        __syncthreads();

        const long obase = (long)g * HPG * 5;
        const long omax  = (long)H * 5;
        for (int i = t; i < HPG * 5; i += 256) {
            const long o = obase + i;
            if (o < omax) {
                const int v = acc[i];
                if (v) atomicXor(&out[o], v);
            }
        }
        __syncthreads();
    }
}

// ---------------- Kernel B (fallback, R10 form): direct 5-dword rows ----------------
__global__ __launch_bounds__(256) void gather_kernel(
    const unsigned int* __restrict__ buck,
    const unsigned int* __restrict__ tab,
    const int* __restrict__ entries,
    int* __restrict__ out,
    int H, int NG, int nSl, int groupsPerBlock)
{
    __shared__ int acc[HPG * 5];

    const int B = blockIdx.x;
    const int x = B & 7;
    const int g0 = B >> 3;
    const int t = threadIdx.x;
    const int gStride = gridDim.x >> 3;

    for (int k = 0; k < groupsPerBlock; ++k) {
        const int g = g0 + k * gStride;
        if (g >= NG) break;

        for (int i = t; i < HPG * 5; i += 256) acc[i] = 0;
        __syncthreads();

        for (int s = x; s < nSl; s += 8) {
            const unsigned int base = tab[(g * NSL + s) * 2 + 0];
            const unsigned int cn   = tab[(g * NSL + s) * 2 + 1];

            unsigned int i = t;
            for (; i + 256 < cn; i += 512) {
                const unsigned int w0 = buck[base + i];
                const unsigned int w1 = buck[base + i + 256];
                const int idx0 = (int)(w0 & 0xFFFFFu);
                const int idx1 = (int)(w1 & 0xFFFFFu);
                const int h0   = (int)(w0 >> 20);
                const int h1   = (int)(w1 >> 20);
                const int* r0 = entries + (long)idx0 * 5;
                const int* r1 = entries + (long)idx1 * 5;
                const int a0 = r0[0], a1 = r0[1], a2 = r0[2], a3 = r0[3], a4 = r0[4];
                const int b0 = r1[0], b1 = r1[1], b2 = r1[2], b3 = r1[3], b4 = r1[4];
                atomicXor(&acc[h0 * 5 + 0], a0);
                atomicXor(&acc[h0 * 5 + 1], a1);
                atomicXor(&acc[h0 * 5 + 2], a2);
                atomicXor(&acc[h0 * 5 + 3], a3);
                atomicXor(&acc[h0 * 5 + 4], a4);
                atomicXor(&acc[h1 * 5 + 0], b0);
                atomicXor(&acc[h1 * 5 + 1], b1);
                atomicXor(&acc[h1 * 5 + 2], b2);
                atomicXor(&acc[h1 * 5 + 3], b3);
                atomicXor(&acc[h1 * 5 + 4], b4);
            }
            if (i < cn) {
                const unsigned int w = buck[base + i];
                const int idx = (int)(w & 0xFFFFFu);
                const int h   = (int)(w >> 20);
                const int* row = entries + (long)idx * 5;
                atomicXor(&acc[h * 5 + 0], row[0]);
                atomicXor(&acc[h * 5 + 1], row[1]);
                atomicXor(&acc[h * 5 + 2], row[2]);
                atomicXor(&acc[h * 5 + 3], row[3]);
                atomicXor(&acc[h * 5 + 4], row[4]);
            }
        }
        __syncthreads();

        const long obase = (long)g * HPG * 5;
        const long omax  = (long)H * 5;
        for (int i = t; i < HPG * 5; i += 256) {
            const long o = obase + i;
            if (o < omax) {
                const int v = acc[i];
                if (v) atomicXor(&out[o], v);
            }
        }
        __syncthreads();
    }
}

// ---------------- Fallback (R1): direct gather, wave per hint ----------------
__global__ __launch_bounds__(256) void hint_xor_wave(
    const int* __restrict__ entries,
    const int* __restrict__ blocks,
    const int* __restrict__ offsets,
    const int* __restrict__ starts,
    const int* __restrict__ sizes,
    const int* __restrict__ bs_ptr,
    int* __restrict__ out,
    int H, int N)
{
    const int gtid = blockIdx.x * blockDim.x + threadIdx.x;
    const int hint = gtid >> 6;
    const int lane = gtid & 63;
    if (hint >= H) return;

    const int start = starts[hint];
    const int size  = sizes[hint];
    const int bs    = bs_ptr[0];

    int a0 = 0, a1 = 0, a2 = 0, a3 = 0, a4 = 0;
    for (int j = lane; j < size; j += 64) {
        int idx = clip_idx(blocks[start + j] * bs + offsets[start + j], N);
        const int* row = entries + (size_t)idx * 5;
        a0 ^= row[0]; a1 ^= row[1]; a2 ^= row[2]; a3 ^= row[3]; a4 ^= row[4];
    }
    #pragma unroll
    for (int m = 1; m < 64; m <<= 1) {
        a0 ^= __shfl_xor(a0, m);
        a1 ^= __shfl_xor(a1, m);
        a2 ^= __shfl_xor(a2, m);
        a3 ^= __shfl_xor(a3, m);
        a4 ^= __shfl_xor(a4, m);
    }
    if (lane == 0) {
        int* o = out + (size_t)hint * 5;
        o[0] = a0; o[1] = a1; o[2] = a2; o[3] = a3; o[4] = a4;
    }
}

extern "C" void kernel_launch(void* const* d_in, const int* in_sizes, int n_in,
                              void* d_out, int out_size, void* d_ws, size_t ws_size,
                              hipStream_t stream) {
    const int* entries = (const int*)d_in[0];
    const int* blocks  = (const int*)d_in[1];
    const int* offsets = (const int*)d_in[2];
    const int* starts  = (const int*)d_in[3];
    const int* sizes   = (const int*)d_in[4];
    const int* bs      = (const int*)d_in[5];
    int* out = (int*)d_out;

    const int H = in_sizes[3];
    const int T = in_sizes[1];
    const int N = in_sizes[0] / 5;

    const int NG  = (H + HPG - 1) / HPG;
    const int nSl = (N + 65535) >> 16;

    // ws layout: buck [T] u32 | tab [NG*NSL*2] u32 | ep [ceil(N/3)] 64B blocks
    const size_t buckOff   = 0;
    const size_t buckBytes = (size_t)T * 4;
    const size_t tabOff    = (buckOff + buckBytes + 63) & ~(size_t)63;
    const size_t tabBytes  = (size_t)NG * NSL * 2 * 4;
    const size_t epOff     = (tabOff + tabBytes + 63) & ~(size_t)63;
    const size_t epBytes   = (size_t)((N + 2) / 3) * 64;
    const size_t needBuck  = tabOff + tabBytes + 64;
    const size_t needPack  = epOff + epBytes + 64;

    const bool okBase = (N <= (1 << 20)) && (nSl <= NSL) && (H <= (1 << 27));
    const bool okPack = okBase && (ws_size >= needPack);
    const bool okBuck = okBase && (ws_size >= needBuck);

    if (okBuck) {
        unsigned int* buck = (unsigned int*)((char*)d_ws + buckOff);
        unsigned int* tab  = (unsigned int*)((char*)d_ws + tabOff);
        int* ep = okPack ? (int*)((char*)d_ws + epOff) : nullptr;

        // out[] is zeroed inside bucket_kernel (per-group) — no memset dispatch.

        hipLaunchKernelGGL(bucket_kernel, dim3(NG), dim3(1024), 0, stream,
                           blocks, offsets, starts, bs, entries, out,
                           buck, tab, ep, H, N, T);

        int gridB = 2048;
        if (gridB > NG * 8) gridB = NG * 8;
        const int gStride = (gridB >= 8) ? (gridB >> 3) : 1;
        const int gpb = (NG + gStride - 1) / gStride;

        if (okPack) {
            hipLaunchKernelGGL(gather_kernel_packed, dim3(gridB), dim3(256), 0, stream,
                               buck, tab, ep, out, H, NG, nSl, gpb);
        } else {
            hipLaunchKernelGGL(gather_kernel, dim3(gridB), dim3(256), 0, stream,
                               buck, tab, entries, out, H, NG, nSl, gpb);
        }
    } else {
        const long total_threads = (long)H * 64;
        const int block = 256;
        const int grid = (int)((total_threads + block - 1) / block);
        hipLaunchKernelGGL(hint_xor_wave, dim3(grid), dim3(block), 0, stream,
                           entries, blocks, offsets, starts, sizes, bs, out, H, N);
    }
}

// Round 7
// 185.722 us; speedup vs baseline: 1.0231x; 1.0231x over previous
//
#include <hip/hip_runtime.h>

// Gather + ragged segment XOR reduction.
// History:
//  R1/R2: direct gather 142 us — L2-miss line-fill bound (table >> 4 MB/XCD L2).
//  R4: slice-bucket + XCD-pinned gather; gather ~60, bucket 67 (occupancy).
//  R5: global-atomic bucketizer regressed (139 MB scattered writes). Reverted.
//  R6: LDS-staged ordered scatter + binary-search labels: bucket ~30, gather
//    61.4, total 189 us (best).
//  R7: padded 32B rows: gather flat (confounded: 32 MB table -> L2 thrash).
//  R8: ballot-aggregated bucket atomics: 30->96 us (VALU-bound). Reverted.
//  R9: 64-bit LDS atomicXor: memory-backed path on gfx950. NEVER use. Reverted.
//  R10: 2-way unrolled gather loop: FLAT => not latency-bound.
//  R12: split e4[int4]+e1[int]: gather 60->90. lines/token 1.125->2.0 =>
//    REGRESSED => gather is L1 LINE-FILL-RATE bound.
//  R13: pack-3 rows/64B line: gather 52.0 (fills/token -> 1.0). Fit:
//    cyc/token = 0.2*lane_reqs + 2.8*fills + ~0.6 DS.
//  R14: nontemporal row loads: gather 120, FETCH 29.7->52.9 MB. HW FACT: nt on
//    gfx950 is evict-first in L2 TOO. NEVER nt-load L2-pinned data. Reverted.
//  R15: sc0 row loads (L1-bypass, L2-normal): gather FLAT 52, FETCH restored.
//    => the ~2.8cyc/line is the miss-processing/TA path, NOT L1 allocate.
//    Gather at ~75-80% of its structural pipe. Accepted.
//  R16: wave-parallel label-fill replacing binary search: FLAT (190.0).
//    With R8: bucket is NOT labeling-bound. Residual bucket cost = global
//    streams (~23us BW floor) + 16-addr LDS atomics + issue.
//  R17 (this): bucket issue-count reduction: int4-vectorized pass-1 loads
//    (scalar prologue/tail for alignment) + repack as straight coalesced
//    dword copy (no div/mod). Gather byte-identical. Pre-committed: if
//    flat (>=188) => declare roofline next round.

#define HPG        128     // hints per group
#define NSL        16      // slices (idx>>16), N <= 2^20
#define STAGE_CAP  12288   // tokens staged in LDS; mean 8192, +10 sigma

typedef int iv4 __attribute__((ext_vector_type(4), aligned(4)));

__device__ __forceinline__ int clip_idx(int v, int N) {
    return min(max(v, 0), N - 1);
}

// ---------------- Kernel A: bucketize (one group per block) + pack-3 repack ----------------
__global__ __launch_bounds__(1024) void bucket_kernel(
    const int* __restrict__ blocks,
    const int* __restrict__ offsets,
    const int* __restrict__ starts,
    const int* __restrict__ bs_ptr,
    const int* __restrict__ entries,     // overflow path + repack source
    int* __restrict__ out,               // zeroed here; overflow path
    unsigned int* __restrict__ buck,     // [T] u32: idx(20) | localHint(<<20)
    unsigned int* __restrict__ tab,      // [NG*NSL*2] {absBase, count}
    int* __restrict__ ep,                // packed table: 3 rows / 64B (may be null)
    int H, int N, int T)
{
    __shared__ unsigned int stage[STAGE_CAP];
    __shared__ int lstart[HPG + 1];
    __shared__ unsigned int cnt[NSL], off[NSL], lcur[NSL];

    const int g  = blockIdx.x;
    const int t  = threadIdx.x;

    // Pack-3 repack as a straight coalesced dword copy:
    // ep dword d -> block q=d>>4, slot u=d&15; payload u<15 maps to
    // entries dword q*15+u (rows 3q..3q+2 contiguous). No div/mod.
    if (ep) {
        const int nq = (N + 2) / 3;
        const long totalD = (long)nq * 16;
        const long nsrc   = (long)N * 5;
        for (long d = (long)blockIdx.x * 1024 + t; d < totalD;
             d += (long)gridDim.x * 1024) {
            const long q = d >> 4;
            const int  u = (int)(d & 15);
            const long src = q * 15 + u;
            int v = 0;
            if (u < 15 && src < nsrc) v = entries[src];
            ep[d] = v;
        }
    }

    const int h0 = g * HPG;
    const int h1 = min(H, h0 + HPG);
    const int nh = h1 - h0;
    const int bs = bs_ptr[0];

    // Zero this group's slice of out (replaces the separate memset dispatch).
    {
        int* oz = out + (long)h0 * 5;
        const int zn = nh * 5;
        for (int i = t; i < zn; i += 1024) oz[i] = 0;
    }

    if (t < nh) lstart[t] = starts[h0 + t];
    if (t == 0) lstart[nh] = (h1 < H) ? starts[h1] : T;
    if (t < NSL) { cnt[t] = 0; lcur[t] = 0; }
    __syncthreads();

    const int tokBase = lstart[0];
    const int count   = lstart[nh] - tokBase;
    const int staged  = min(count, STAGE_CAP);

    // phase 0: wave-parallel hint-label fill (R16). Wave w handles hints
    // h = w, w+16, ...: lanes write (h<<20) across the hint's token span.
    {
        const int wave = t >> 6;
        const int lane = t & 63;
        for (int h = wave; h < nh; h += 16) {
            const int s0 = lstart[h]     - tokBase;
            const int s1 = min(lstart[h + 1] - tokBase, staged);
            const unsigned int lab = (unsigned int)h << 20;
            for (int i = s0 + lane; i < s1; i += 64) stage[i] = lab;
        }
    }
    __syncthreads();

    // pass 1: idx -> OR into labelled stage; per-slice histogram.
    // int4-vectorized global loads with scalar prologue/tail for alignment.
    {
        const int pre = min(staged, (4 - (tokBase & 3)) & 3);
        for (int i = t; i < pre; i += 1024) {
            const int gpos = tokBase + i;
            const int idx  = clip_idx(blocks[gpos] * bs + offsets[gpos], N);
            stage[i] |= (unsigned int)idx;
            atomicAdd(&cnt[(unsigned int)idx >> 16], 1u);
        }
        const int vecN = (staged - pre) >> 2;
        const int4* vb = (const int4*)(blocks  + tokBase + pre);
        const int4* vo = (const int4*)(offsets + tokBase + pre);
        for (int v = t; v < vecN; v += 1024) {
            const int4 b4 = vb[v];
            const int4 o4 = vo[v];
            const int i0 = pre + (v << 2);
            int idx;
            idx = clip_idx(b4.x * bs + o4.x, N);
            stage[i0 + 0] |= (unsigned int)idx;
            atomicAdd(&cnt[(unsigned int)idx >> 16], 1u);
            idx = clip_idx(b4.y * bs + o4.y, N);
            stage[i0 + 1] |= (unsigned int)idx;
            atomicAdd(&cnt[(unsigned int)idx >> 16], 1u);
            idx = clip_idx(b4.z * bs + o4.z, N);
            stage[i0 + 2] |= (unsigned int)idx;
            atomicAdd(&cnt[(unsigned int)idx >> 16], 1u);
            idx = clip_idx(b4.w * bs + o4.w, N);
            stage[i0 + 3] |= (unsigned int)idx;
            atomicAdd(&cnt[(unsigned int)idx >> 16], 1u);
        }
        for (int i = pre + (vecN << 2) + t; i < staged; i += 1024) {
            const int gpos = tokBase + i;
            const int idx  = clip_idx(blocks[gpos] * bs + offsets[gpos], N);
            stage[i] |= (unsigned int)idx;
            atomicAdd(&cnt[(unsigned int)idx >> 16], 1u);
        }
    }
    __syncthreads();

    // exclusive prefix over 16 slice counts
    if (t == 0) {
        unsigned int run = 0;
        for (int s = 0; s < NSL; ++s) { off[s] = run; run += cnt[s]; }
    }
    __syncthreads();

    if (t < NSL) {
        tab[(g * NSL + t) * 2 + 0] = (unsigned int)tokBase + off[t];
        tab[(g * NSL + t) * 2 + 1] = cnt[t];
    }

    // pass 2: ordered scatter into the group's own CSR range
    for (int i = t; i < staged; i += 1024) {
        const unsigned int w = stage[i];
        const unsigned int s = (w >> 16) & (NSL - 1);
        const unsigned int r = atomicAdd(&lcur[s], 1u);
        buck[(unsigned int)tokBase + off[s] + r] = w;
    }

    // overflow remainder (count > STAGE_CAP): statistically never; correctness.
    for (int i = staged + t; i < count; i += 1024) {
        const int gpos = tokBase + i;
        const int idx  = clip_idx(blocks[gpos] * bs + offsets[gpos], N);
        int lo = 0, hi = nh - 1;
        while (lo < hi) {
            int m = (lo + hi + 1) >> 1;
            if (lstart[m] <= gpos) lo = m; else hi = m - 1;
        }
        const int* row = entries + (long)idx * 5;
        int* o5 = out + (long)(h0 + lo) * 5;
        atomicXor(&o5[0], row[0]); atomicXor(&o5[1], row[1]);
        atomicXor(&o5[2], row[2]); atomicXor(&o5[3], row[3]);
        atomicXor(&o5[4], row[4]);
    }
}

// ---------------- Kernel B (packed): XCD-pinned gather + LDS accumulate ----------------
// Grid = 2048 (resident capacity) so blockIdx&7 -> XCD round-robin holds.
// Block (x,g) touches only slices {x, x+8} -> ~2.9 MB packed rows, L2-resident.
// Per token: ONE line; rows read with sc0 (L1-bypass, L2-normal).
__global__ __launch_bounds__(256) void gather_kernel_packed(
    const unsigned int* __restrict__ buck,
    const unsigned int* __restrict__ tab,
    const int* __restrict__ ep,
    int* __restrict__ out,
    int H, int NG, int nSl, int groupsPerBlock)
{
    __shared__ int acc[HPG * 5];

    const int B = blockIdx.x;
    const int x = B & 7;
    const int g0 = B >> 3;
    const int t = threadIdx.x;
    const int gStride = gridDim.x >> 3;

    for (int k = 0; k < groupsPerBlock; ++k) {
        const int g = g0 + k * gStride;
        if (g >= NG) break;

        for (int i = t; i < HPG * 5; i += 256) acc[i] = 0;
        __syncthreads();

        for (int s = x; s < nSl; s += 8) {
            const unsigned int base = tab[(g * NSL + s) * 2 + 0];
            const unsigned int cn   = tab[(g * NSL + s) * 2 + 1];

            unsigned int i = t;
            for (; i + 256 < cn; i += 512) {
                const unsigned int w0 = buck[base + i];
                const unsigned int w1 = buck[base + i + 256];
                const unsigned int idx0 = w0 & 0xFFFFFu;
                const unsigned int idx1 = w1 & 0xFFFFFu;
                const int h0 = (int)(w0 >> 20);
                const int h1 = (int)(w1 >> 20);
                const unsigned int q0 = idx0 / 3u, m0 = idx0 - q0 * 3u;
                const unsigned int q1 = idx1 / 3u, m1 = idx1 - q1 * 3u;
                const int* r0 = ep + (size_t)q0 * 16 + m0 * 5;
                const int* r1 = ep + (size_t)q1 * 16 + m1 * 5;
                // sc0: bypass L1 allocate, normal L2 caching. One address
                // per row; col4 via offset:16 from the same line.
                iv4 a, b; int a4, b4;
                asm volatile(
                    "global_load_dwordx4 %0, %4, off sc0\n\t"
                    "global_load_dword   %1, %4, off offset:16 sc0\n\t"
                    "global_load_dwordx4 %2, %5, off sc0\n\t"
                    "global_load_dword   %3, %5, off offset:16 sc0\n\t"
                    "s_waitcnt vmcnt(0)"
                    : "=&v"(a), "=&v"(a4), "=&v"(b), "=&v"(b4)
                    : "v"(r0), "v"(r1)
                    : "memory");
                atomicXor(&acc[h0 * 5 + 0], a.x);
                atomicXor(&acc[h0 * 5 + 1], a.y);
                atomicXor(&acc[h0 * 5 + 2], a.z);
                atomicXor(&acc[h0 * 5 + 3], a.w);
                atomicXor(&acc[h0 * 5 + 4], a4);
                atomicXor(&acc[h1 * 5 + 0], b.x);
                atomicXor(&acc[h1 * 5 + 1], b.y);
                atomicXor(&acc[h1 * 5 + 2], b.z);
                atomicXor(&acc[h1 * 5 + 3], b.w);
                atomicXor(&acc[h1 * 5 + 4], b4);
            }
            if (i < cn) {
                const unsigned int w = buck[base + i];
                const unsigned int idx = w & 0xFFFFFu;
                const int h = (int)(w >> 20);
                const unsigned int q = idx / 3u, m = idx - q * 3u;
                const int* r0 = ep + (size_t)q * 16 + m * 5;
                iv4 a; int a4;
                asm volatile(
                    "global_load_dwordx4 %0, %2, off sc0\n\t"
                    "global_load_dword   %1, %2, off offset:16 sc0\n\t"
                    "s_waitcnt vmcnt(0)"
                    : "=&v"(a), "=&v"(a4)
                    : "v"(r0)
                    : "memory");
                atomicXor(&acc[h * 5 + 0], a.x);
                atomicXor(&acc[h * 5 + 1], a.y);
                atomicXor(&acc[h * 5 + 2], a.z);
                atomicXor(&acc[h * 5 + 3], a.w);
                atomicXor(&acc[h * 5 + 4], a4);
            }
        }
        __syncthreads();

        const long obase = (long)g * HPG * 5;
        const long omax  = (long)H * 5;
        for (int i = t; i < HPG * 5; i += 256) {
            const long o = obase + i;
            if (o < omax) {
                const int v = acc[i];
                if (v) atomicXor(&out[o], v);
            }
        }
        __syncthreads();
    }
}

// ---------------- Kernel B (fallback, R10 form): direct 5-dword rows ----------------
__global__ __launch_bounds__(256) void gather_kernel(
    const unsigned int* __restrict__ buck,
    const unsigned int* __restrict__ tab,
    const int* __restrict__ entries,
    int* __restrict__ out,
    int H, int NG, int nSl, int groupsPerBlock)
{
    __shared__ int acc[HPG * 5];

    const int B = blockIdx.x;
    const int x = B & 7;
    const int g0 = B >> 3;
    const int t = threadIdx.x;
    const int gStride = gridDim.x >> 3;

    for (int k = 0; k < groupsPerBlock; ++k) {
        const int g = g0 + k * gStride;
        if (g >= NG) break;

        for (int i = t; i < HPG * 5; i += 256) acc[i] = 0;
        __syncthreads();

        for (int s = x; s < nSl; s += 8) {
            const unsigned int base = tab[(g * NSL + s) * 2 + 0];
            const unsigned int cn   = tab[(g * NSL + s) * 2 + 1];

            unsigned int i = t;
            for (; i + 256 < cn; i += 512) {
                const unsigned int w0 = buck[base + i];
                const unsigned int w1 = buck[base + i + 256];
                const int idx0 = (int)(w0 & 0xFFFFFu);
                const int idx1 = (int)(w1 & 0xFFFFFu);
                const int h0   = (int)(w0 >> 20);
                const int h1   = (int)(w1 >> 20);
                const int* r0 = entries + (long)idx0 * 5;
                const int* r1 = entries + (long)idx1 * 5;
                const int a0 = r0[0], a1 = r0[1], a2 = r0[2], a3 = r0[3], a4 = r0[4];
                const int b0 = r1[0], b1 = r1[1], b2 = r1[2], b3 = r1[3], b4 = r1[4];
                atomicXor(&acc[h0 * 5 + 0], a0);
                atomicXor(&acc[h0 * 5 + 1], a1);
                atomicXor(&acc[h0 * 5 + 2], a2);
                atomicXor(&acc[h0 * 5 + 3], a3);
                atomicXor(&acc[h0 * 5 + 4], a4);
                atomicXor(&acc[h1 * 5 + 0], b0);
                atomicXor(&acc[h1 * 5 + 1], b1);
                atomicXor(&acc[h1 * 5 + 2], b2);
                atomicXor(&acc[h1 * 5 + 3], b3);
                atomicXor(&acc[h1 * 5 + 4], b4);
            }
            if (i < cn) {
                const unsigned int w = buck[base + i];
                const int idx = (int)(w & 0xFFFFFu);
                const int h   = (int)(w >> 20);
                const int* row = entries + (long)idx * 5;
                atomicXor(&acc[h * 5 + 0], row[0]);
                atomicXor(&acc[h * 5 + 1], row[1]);
                atomicXor(&acc[h * 5 + 2], row[2]);
                atomicXor(&acc[h * 5 + 3], row[3]);
                atomicXor(&acc[h * 5 + 4], row[4]);
            }
        }
        __syncthreads();

        const long obase = (long)g * HPG * 5;
        const long omax  = (long)H * 5;
        for (int i = t; i < HPG * 5; i += 256) {
            const long o = obase + i;
            if (o < omax) {
                const int v = acc[i];
                if (v) atomicXor(&out[o], v);
            }
        }
        __syncthreads();
    }
}

// ---------------- Fallback (R1): direct gather, wave per hint ----------------
__global__ __launch_bounds__(256) void hint_xor_wave(
    const int* __restrict__ entries,
    const int* __restrict__ blocks,
    const int* __restrict__ offsets,
    const int* __restrict__ starts,
    const int* __restrict__ sizes,
    const int* __restrict__ bs_ptr,
    int* __restrict__ out,
    int H, int N)
{
    const int gtid = blockIdx.x * blockDim.x + threadIdx.x;
    const int hint = gtid >> 6;
    const int lane = gtid & 63;
    if (hint >= H) return;

    const int start = starts[hint];
    const int size  = sizes[hint];
    const int bs    = bs_ptr[0];

    int a0 = 0, a1 = 0, a2 = 0, a3 = 0, a4 = 0;
    for (int j = lane; j < size; j += 64) {
        int idx = clip_idx(blocks[start + j] * bs + offsets[start + j], N);
        const int* row = entries + (size_t)idx * 5;
        a0 ^= row[0]; a1 ^= row[1]; a2 ^= row[2]; a3 ^= row[3]; a4 ^= row[4];
    }
    #pragma unroll
    for (int m = 1; m < 64; m <<= 1) {
        a0 ^= __shfl_xor(a0, m);
        a1 ^= __shfl_xor(a1, m);
        a2 ^= __shfl_xor(a2, m);
        a3 ^= __shfl_xor(a3, m);
        a4 ^= __shfl_xor(a4, m);
    }
    if (lane == 0) {
        int* o = out + (size_t)hint * 5;
        o[0] = a0; o[1] = a1; o[2] = a2; o[3] = a3; o[4] = a4;
    }
}

extern "C" void kernel_launch(void* const* d_in, const int* in_sizes, int n_in,
                              void* d_out, int out_size, void* d_ws, size_t ws_size,
                              hipStream_t stream) {
    const int* entries = (const int*)d_in[0];
    const int* blocks  = (const int*)d_in[1];
    const int* offsets = (const int*)d_in[2];
    const int* starts  = (const int*)d_in[3];
    const int* sizes   = (const int*)d_in[4];
    const int* bs      = (const int*)d_in[5];
    int* out = (int*)d_out;

    const int H = in_sizes[3];
    const int T = in_sizes[1];
    const int N = in_sizes[0] / 5;

    const int NG  = (H + HPG - 1) / HPG;
    const int nSl = (N + 65535) >> 16;

    // ws layout: buck [T] u32 | tab [NG*NSL*2] u32 | ep [ceil(N/3)] 64B blocks
    const size_t buckOff   = 0;
    const size_t buckBytes = (size_t)T * 4;
    const size_t tabOff    = (buckOff + buckBytes + 63) & ~(size_t)63;
    const size_t tabBytes  = (size_t)NG * NSL * 2 * 4;
    const size_t epOff     = (tabOff + tabBytes + 63) & ~(size_t)63;
    const size_t epBytes   = (size_t)((N + 2) / 3) * 64;
    const size_t needBuck  = tabOff + tabBytes + 64;
    const size_t needPack  = epOff + epBytes + 64;

    const bool okBase = (N <= (1 << 20)) && (nSl <= NSL) && (H <= (1 << 27));
    const bool okPack = okBase && (ws_size >= needPack);
    const bool okBuck = okBase && (ws_size >= needBuck);

    if (okBuck) {
        unsigned int* buck = (unsigned int*)((char*)d_ws + buckOff);
        unsigned int* tab  = (unsigned int*)((char*)d_ws + tabOff);
        int* ep = okPack ? (int*)((char*)d_ws + epOff) : nullptr;

        // out[] is zeroed inside bucket_kernel (per-group) — no memset dispatch.

        hipLaunchKernelGGL(bucket_kernel, dim3(NG), dim3(1024), 0, stream,
                           blocks, offsets, starts, bs, entries, out,
                           buck, tab, ep, H, N, T);

        int gridB = 2048;
        if (gridB > NG * 8) gridB = NG * 8;
        const int gStride = (gridB >= 8) ? (gridB >> 3) : 1;
        const int gpb = (NG + gStride - 1) / gStride;

        if (okPack) {
            hipLaunchKernelGGL(gather_kernel_packed, dim3(gridB), dim3(256), 0, stream,
                               buck, tab, ep, out, H, NG, nSl, gpb);
        } else {
            hipLaunchKernelGGL(gather_kernel, dim3(gridB), dim3(256), 0, stream,
                               buck, tab, entries, out, H, NG, nSl, gpb);
        }
    } else {
        const long total_threads = (long)H * 64;
        const int block = 256;
        const int grid = (int)((total_threads + block - 1) / block);
        hipLaunchKernelGGL(hint_xor_wave, dim3(grid), dim3(block), 0, stream,
                           entries, blocks, offsets, starts, sizes, bs, out, H, N);
    }
}

// Round 8
// 184.615 us; speedup vs baseline: 1.0292x; 1.0060x over previous
//
#include <hip/hip_runtime.h>

// Gather + ragged segment XOR reduction.
// History:
//  R1/R2: direct gather 142 us — L2-miss line-fill bound (table >> 4 MB/XCD L2).
//  R4: slice-bucket + XCD-pinned gather; gather ~60, bucket 67 (occupancy).
//  R5: global-atomic bucketizer regressed (139 MB scattered writes). Reverted.
//  R6: LDS-staged ordered scatter + binary-search labels: bucket ~30, gather
//    61.4, total 189 us (best).
//  R7: padded 32B rows: gather flat (confounded: 32 MB table -> L2 thrash).
//  R8: ballot-aggregated bucket atomics: 30->96 us (VALU-bound). Reverted.
//  R9: 64-bit LDS atomicXor: memory-backed path on gfx950. NEVER use. Reverted.
//  R10: 2-way unrolled gather loop: FLAT => not latency-bound.
//  R12: split e4[int4]+e1[int]: gather 60->90. lines/token 1.125->2.0 =>
//    REGRESSED => gather is L1 LINE-FILL-RATE bound.
//  R13: pack-3 rows/64B line: gather 52.0 (fills/token -> 1.0). Fit:
//    cyc/token = 0.2*lane_reqs + 2.8*fills + ~0.6 DS.
//  R14: nontemporal row loads: gather 120, FETCH 29.7->52.9 MB. HW FACT: nt on
//    gfx950 is evict-first in L2 TOO. NEVER nt-load L2-pinned data. Reverted.
//  R15: sc0 row loads (L1-bypass, L2-normal): gather FLAT 52, FETCH restored.
//    => the ~2.8cyc/line is the miss-processing/TA path, NOT L1 allocate.
//    Gather at ~75-80% of its structural pipe. Accepted.
//  R16: wave-parallel label-fill replacing binary search: FLAT (190.0).
//    With R8: bucket is NOT labeling-bound.
//  R17: int4 pass-1 loads + copy-style repack: 185.7 (-4). Bucket is
//    stream-BW + issue bound (~34us vs ~23us BW floor).
//  R18 (this): final bucket polish: (a) repack moved at int4 granularity
//    (dword 15/block is pad gather never reads -> no masking, only end
//    guard); (b) stage[i]|=idx -> atomicOr (single non-returning ds_or
//    vs ds_read+or+ds_write). Gather byte-identical. Exit rule: if gain
//    <2us, declare roofline next round.

#define HPG        128     // hints per group
#define NSL        16      // slices (idx>>16), N <= 2^20
#define STAGE_CAP  12288   // tokens staged in LDS; mean 8192, +10 sigma

typedef int iv4 __attribute__((ext_vector_type(4), aligned(4)));

__device__ __forceinline__ int clip_idx(int v, int N) {
    return min(max(v, 0), N - 1);
}

// ---------------- Kernel A: bucketize (one group per block) + pack-3 repack ----------------
__global__ __launch_bounds__(1024) void bucket_kernel(
    const int* __restrict__ blocks,
    const int* __restrict__ offsets,
    const int* __restrict__ starts,
    const int* __restrict__ bs_ptr,
    const int* __restrict__ entries,     // overflow path + repack source
    int* __restrict__ out,               // zeroed here; overflow path
    unsigned int* __restrict__ buck,     // [T] u32: idx(20) | localHint(<<20)
    unsigned int* __restrict__ tab,      // [NG*NSL*2] {absBase, count}
    int* __restrict__ ep,                // packed table: 3 rows / 64B (may be null)
    int H, int N, int T)
{
    __shared__ unsigned int stage[STAGE_CAP];
    __shared__ int lstart[HPG + 1];
    __shared__ unsigned int cnt[NSL], off[NSL], lcur[NSL];

    const int g  = blockIdx.x;
    const int t  = threadIdx.x;

    // Pack-3 repack at int4 granularity. int4 slot v: block q=v>>2,
    // quarter u4=v&3; src dword q*15+4*u4. Dword 15 of each 64B block is
    // pad that gather never reads, so the u4==3 slot may carry one garbage
    // dword from the next rows — harmless. Only guard the array end.
    if (ep) {
        const int  nq     = (N + 2) / 3;
        const long totalV = (long)nq * 4;
        const long nsrc   = (long)N * 5;
        iv4* ep4 = (iv4*)ep;
        for (long v = (long)blockIdx.x * 1024 + t; v < totalV;
             v += (long)gridDim.x * 1024) {
            const long q  = v >> 2;
            const int  u4 = (int)(v & 3);
            const long src = q * 15 + 4 * u4;
            iv4 val;
            if (src + 4 <= nsrc) {
                val = *(const iv4*)(entries + src);
            } else {
                val.x = (src + 0 < nsrc) ? entries[src + 0] : 0;
                val.y = (src + 1 < nsrc) ? entries[src + 1] : 0;
                val.z = (src + 2 < nsrc) ? entries[src + 2] : 0;
                val.w = (src + 3 < nsrc) ? entries[src + 3] : 0;
            }
            ep4[v] = val;
        }
    }

    const int h0 = g * HPG;
    const int h1 = min(H, h0 + HPG);
    const int nh = h1 - h0;
    const int bs = bs_ptr[0];

    // Zero this group's slice of out (replaces the separate memset dispatch).
    {
        int* oz = out + (long)h0 * 5;
        const int zn = nh * 5;
        for (int i = t; i < zn; i += 1024) oz[i] = 0;
    }

    if (t < nh) lstart[t] = starts[h0 + t];
    if (t == 0) lstart[nh] = (h1 < H) ? starts[h1] : T;
    if (t < NSL) { cnt[t] = 0; lcur[t] = 0; }
    __syncthreads();

    const int tokBase = lstart[0];
    const int count   = lstart[nh] - tokBase;
    const int staged  = min(count, STAGE_CAP);

    // phase 0: wave-parallel hint-label fill (R16). Wave w handles hints
    // h = w, w+16, ...: lanes write (h<<20) across the hint's token span.
    {
        const int wave = t >> 6;
        const int lane = t & 63;
        for (int h = wave; h < nh; h += 16) {
            const int s0 = lstart[h]     - tokBase;
            const int s1 = min(lstart[h + 1] - tokBase, staged);
            const unsigned int lab = (unsigned int)h << 20;
            for (int i = s0 + lane; i < s1; i += 64) stage[i] = lab;
        }
    }
    __syncthreads();

    // pass 1: idx -> atomicOr into labelled stage (single ds_or, no return);
    // per-slice histogram. int4-vectorized global loads w/ prologue/tail.
    {
        const int pre = min(staged, (4 - (tokBase & 3)) & 3);
        for (int i = t; i < pre; i += 1024) {
            const int gpos = tokBase + i;
            const int idx  = clip_idx(blocks[gpos] * bs + offsets[gpos], N);
            atomicOr(&stage[i], (unsigned int)idx);
            atomicAdd(&cnt[(unsigned int)idx >> 16], 1u);
        }
        const int vecN = (staged - pre) >> 2;
        const int4* vb = (const int4*)(blocks  + tokBase + pre);
        const int4* vo = (const int4*)(offsets + tokBase + pre);
        for (int v = t; v < vecN; v += 1024) {
            const int4 b4 = vb[v];
            const int4 o4 = vo[v];
            const int i0 = pre + (v << 2);
            int idx;
            idx = clip_idx(b4.x * bs + o4.x, N);
            atomicOr(&stage[i0 + 0], (unsigned int)idx);
            atomicAdd(&cnt[(unsigned int)idx >> 16], 1u);
            idx = clip_idx(b4.y * bs + o4.y, N);
            atomicOr(&stage[i0 + 1], (unsigned int)idx);
            atomicAdd(&cnt[(unsigned int)idx >> 16], 1u);
            idx = clip_idx(b4.z * bs + o4.z, N);
            atomicOr(&stage[i0 + 2], (unsigned int)idx);
            atomicAdd(&cnt[(unsigned int)idx >> 16], 1u);
            idx = clip_idx(b4.w * bs + o4.w, N);
            atomicOr(&stage[i0 + 3], (unsigned int)idx);
            atomicAdd(&cnt[(unsigned int)idx >> 16], 1u);
        }
        for (int i = pre + (vecN << 2) + t; i < staged; i += 1024) {
            const int gpos = tokBase + i;
            const int idx  = clip_idx(blocks[gpos] * bs + offsets[gpos], N);
            atomicOr(&stage[i], (unsigned int)idx);
            atomicAdd(&cnt[(unsigned int)idx >> 16], 1u);
        }
    }
    __syncthreads();

    // exclusive prefix over 16 slice counts
    if (t == 0) {
        unsigned int run = 0;
        for (int s = 0; s < NSL; ++s) { off[s] = run; run += cnt[s]; }
    }
    __syncthreads();

    if (t < NSL) {
        tab[(g * NSL + t) * 2 + 0] = (unsigned int)tokBase + off[t];
        tab[(g * NSL + t) * 2 + 1] = cnt[t];
    }

    // pass 2: ordered scatter into the group's own CSR range
    for (int i = t; i < staged; i += 1024) {
        const unsigned int w = stage[i];
        const unsigned int s = (w >> 16) & (NSL - 1);
        const unsigned int r = atomicAdd(&lcur[s], 1u);
        buck[(unsigned int)tokBase + off[s] + r] = w;
    }

    // overflow remainder (count > STAGE_CAP): statistically never; correctness.
    for (int i = staged + t; i < count; i += 1024) {
        const int gpos = tokBase + i;
        const int idx  = clip_idx(blocks[gpos] * bs + offsets[gpos], N);
        int lo = 0, hi = nh - 1;
        while (lo < hi) {
            int m = (lo + hi + 1) >> 1;
            if (lstart[m] <= gpos) lo = m; else hi = m - 1;
        }
        const int* row = entries + (long)idx * 5;
        int* o5 = out + (long)(h0 + lo) * 5;
        atomicXor(&o5[0], row[0]); atomicXor(&o5[1], row[1]);
        atomicXor(&o5[2], row[2]); atomicXor(&o5[3], row[3]);
        atomicXor(&o5[4], row[4]);
    }
}

// ---------------- Kernel B (packed): XCD-pinned gather + LDS accumulate ----------------
// Grid = 2048 (resident capacity) so blockIdx&7 -> XCD round-robin holds.
// Block (x,g) touches only slices {x, x+8} -> ~2.9 MB packed rows, L2-resident.
// Per token: ONE line; rows read with sc0 (L1-bypass, L2-normal).
__global__ __launch_bounds__(256) void gather_kernel_packed(
    const unsigned int* __restrict__ buck,
    const unsigned int* __restrict__ tab,
    const int* __restrict__ ep,
    int* __restrict__ out,
    int H, int NG, int nSl, int groupsPerBlock)
{
    __shared__ int acc[HPG * 5];

    const int B = blockIdx.x;
    const int x = B & 7;
    const int g0 = B >> 3;
    const int t = threadIdx.x;
    const int gStride = gridDim.x >> 3;

    for (int k = 0; k < groupsPerBlock; ++k) {
        const int g = g0 + k * gStride;
        if (g >= NG) break;

        for (int i = t; i < HPG * 5; i += 256) acc[i] = 0;
        __syncthreads();

        for (int s = x; s < nSl; s += 8) {
            const unsigned int base = tab[(g * NSL + s) * 2 + 0];
            const unsigned int cn   = tab[(g * NSL + s) * 2 + 1];

            unsigned int i = t;
            for (; i + 256 < cn; i += 512) {
                const unsigned int w0 = buck[base + i];
                const unsigned int w1 = buck[base + i + 256];
                const unsigned int idx0 = w0 & 0xFFFFFu;
                const unsigned int idx1 = w1 & 0xFFFFFu;
                const int h0 = (int)(w0 >> 20);
                const int h1 = (int)(w1 >> 20);
                const unsigned int q0 = idx0 / 3u, m0 = idx0 - q0 * 3u;
                const unsigned int q1 = idx1 / 3u, m1 = idx1 - q1 * 3u;
                const int* r0 = ep + (size_t)q0 * 16 + m0 * 5;
                const int* r1 = ep + (size_t)q1 * 16 + m1 * 5;
                // sc0: bypass L1 allocate, normal L2 caching. One address
                // per row; col4 via offset:16 from the same line.
                iv4 a, b; int a4, b4;
                asm volatile(
                    "global_load_dwordx4 %0, %4, off sc0\n\t"
                    "global_load_dword   %1, %4, off offset:16 sc0\n\t"
                    "global_load_dwordx4 %2, %5, off sc0\n\t"
                    "global_load_dword   %3, %5, off offset:16 sc0\n\t"
                    "s_waitcnt vmcnt(0)"
                    : "=&v"(a), "=&v"(a4), "=&v"(b), "=&v"(b4)
                    : "v"(r0), "v"(r1)
                    : "memory");
                atomicXor(&acc[h0 * 5 + 0], a.x);
                atomicXor(&acc[h0 * 5 + 1], a.y);
                atomicXor(&acc[h0 * 5 + 2], a.z);
                atomicXor(&acc[h0 * 5 + 3], a.w);
                atomicXor(&acc[h0 * 5 + 4], a4);
                atomicXor(&acc[h1 * 5 + 0], b.x);
                atomicXor(&acc[h1 * 5 + 1], b.y);
                atomicXor(&acc[h1 * 5 + 2], b.z);
                atomicXor(&acc[h1 * 5 + 3], b.w);
                atomicXor(&acc[h1 * 5 + 4], b4);
            }
            if (i < cn) {
                const unsigned int w = buck[base + i];
                const unsigned int idx = w & 0xFFFFFu;
                const int h = (int)(w >> 20);
                const unsigned int q = idx / 3u, m = idx - q * 3u;
                const int* r0 = ep + (size_t)q * 16 + m * 5;
                iv4 a; int a4;
                asm volatile(
                    "global_load_dwordx4 %0, %2, off sc0\n\t"
                    "global_load_dword   %1, %2, off offset:16 sc0\n\t"
                    "s_waitcnt vmcnt(0)"
                    : "=&v"(a), "=&v"(a4)
                    : "v"(r0)
                    : "memory");
                atomicXor(&acc[h * 5 + 0], a.x);
                atomicXor(&acc[h * 5 + 1], a.y);
                atomicXor(&acc[h * 5 + 2], a.z);
                atomicXor(&acc[h * 5 + 3], a.w);
                atomicXor(&acc[h * 5 + 4], a4);
            }
        }
        __syncthreads();

        const long obase = (long)g * HPG * 5;
        const long omax  = (long)H * 5;
        for (int i = t; i < HPG * 5; i += 256) {
            const long o = obase + i;
            if (o < omax) {
                const int v = acc[i];
                if (v) atomicXor(&out[o], v);
            }
        }
        __syncthreads();
    }
}

// ---------------- Kernel B (fallback, R10 form): direct 5-dword rows ----------------
__global__ __launch_bounds__(256) void gather_kernel(
    const unsigned int* __restrict__ buck,
    const unsigned int* __restrict__ tab,
    const int* __restrict__ entries,
    int* __restrict__ out,
    int H, int NG, int nSl, int groupsPerBlock)
{
    __shared__ int acc[HPG * 5];

    const int B = blockIdx.x;
    const int x = B & 7;
    const int g0 = B >> 3;
    const int t = threadIdx.x;
    const int gStride = gridDim.x >> 3;

    for (int k = 0; k < groupsPerBlock; ++k) {
        const int g = g0 + k * gStride;
        if (g >= NG) break;

        for (int i = t; i < HPG * 5; i += 256) acc[i] = 0;
        __syncthreads();

        for (int s = x; s < nSl; s += 8) {
            const unsigned int base = tab[(g * NSL + s) * 2 + 0];
            const unsigned int cn   = tab[(g * NSL + s) * 2 + 1];

            unsigned int i = t;
            for (; i + 256 < cn; i += 512) {
                const unsigned int w0 = buck[base + i];
                const unsigned int w1 = buck[base + i + 256];
                const int idx0 = (int)(w0 & 0xFFFFFu);
                const int idx1 = (int)(w1 & 0xFFFFFu);
                const int h0   = (int)(w0 >> 20);
                const int h1   = (int)(w1 >> 20);
                const int* r0 = entries + (long)idx0 * 5;
                const int* r1 = entries + (long)idx1 * 5;
                const int a0 = r0[0], a1 = r0[1], a2 = r0[2], a3 = r0[3], a4 = r0[4];
                const int b0 = r1[0], b1 = r1[1], b2 = r1[2], b3 = r1[3], b4 = r1[4];
                atomicXor(&acc[h0 * 5 + 0], a0);
                atomicXor(&acc[h0 * 5 + 1], a1);
                atomicXor(&acc[h0 * 5 + 2], a2);
                atomicXor(&acc[h0 * 5 + 3], a3);
                atomicXor(&acc[h0 * 5 + 4], a4);
                atomicXor(&acc[h1 * 5 + 0], b0);
                atomicXor(&acc[h1 * 5 + 1], b1);
                atomicXor(&acc[h1 * 5 + 2], b2);
                atomicXor(&acc[h1 * 5 + 3], b3);
                atomicXor(&acc[h1 * 5 + 4], b4);
            }
            if (i < cn) {
                const unsigned int w = buck[base + i];
                const int idx = (int)(w & 0xFFFFFu);
                const int h   = (int)(w >> 20);
                const int* row = entries + (long)idx * 5;
                atomicXor(&acc[h * 5 + 0], row[0]);
                atomicXor(&acc[h * 5 + 1], row[1]);
                atomicXor(&acc[h * 5 + 2], row[2]);
                atomicXor(&acc[h * 5 + 3], row[3]);
                atomicXor(&acc[h * 5 + 4], row[4]);
            }
        }
        __syncthreads();

        const long obase = (long)g * HPG * 5;
        const long omax  = (long)H * 5;
        for (int i = t; i < HPG * 5; i += 256) {
            const long o = obase + i;
            if (o < omax) {
                const int v = acc[i];
                if (v) atomicXor(&out[o], v);
            }
        }
        __syncthreads();
    }
}

// ---------------- Fallback (R1): direct gather, wave per hint ----------------
__global__ __launch_bounds__(256) void hint_xor_wave(
    const int* __restrict__ entries,
    const int* __restrict__ blocks,
    const int* __restrict__ offsets,
    const int* __restrict__ starts,
    const int* __restrict__ sizes,
    const int* __restrict__ bs_ptr,
    int* __restrict__ out,
    int H, int N)
{
    const int gtid = blockIdx.x * blockDim.x + threadIdx.x;
    const int hint = gtid >> 6;
    const int lane = gtid & 63;
    if (hint >= H) return;

    const int start = starts[hint];
    const int size  = sizes[hint];
    const int bs    = bs_ptr[0];

    int a0 = 0, a1 = 0, a2 = 0, a3 = 0, a4 = 0;
    for (int j = lane; j < size; j += 64) {
        int idx = clip_idx(blocks[start + j] * bs + offsets[start + j], N);
        const int* row = entries + (size_t)idx * 5;
        a0 ^= row[0]; a1 ^= row[1]; a2 ^= row[2]; a3 ^= row[3]; a4 ^= row[4];
    }
    #pragma unroll
    for (int m = 1; m < 64; m <<= 1) {
        a0 ^= __shfl_xor(a0, m);
        a1 ^= __shfl_xor(a1, m);
        a2 ^= __shfl_xor(a2, m);
        a3 ^= __shfl_xor(a3, m);
        a4 ^= __shfl_xor(a4, m);
    }
    if (lane == 0) {
        int* o = out + (size_t)hint * 5;
        o[0] = a0; o[1] = a1; o[2] = a2; o[3] = a3; o[4] = a4;
    }
}

extern "C" void kernel_launch(void* const* d_in, const int* in_sizes, int n_in,
                              void* d_out, int out_size, void* d_ws, size_t ws_size,
                              hipStream_t stream) {
    const int* entries = (const int*)d_in[0];
    const int* blocks  = (const int*)d_in[1];
    const int* offsets = (const int*)d_in[2];
    const int* starts  = (const int*)d_in[3];
    const int* sizes   = (const int*)d_in[4];
    const int* bs      = (const int*)d_in[5];
    int* out = (int*)d_out;

    const int H = in_sizes[3];
    const int T = in_sizes[1];
    const int N = in_sizes[0] / 5;

    const int NG  = (H + HPG - 1) / HPG;
    const int nSl = (N + 65535) >> 16;

    // ws layout: buck [T] u32 | tab [NG*NSL*2] u32 | ep [ceil(N/3)] 64B blocks
    const size_t buckOff   = 0;
    const size_t buckBytes = (size_t)T * 4;
    const size_t tabOff    = (buckOff + buckBytes + 63) & ~(size_t)63;
    const size_t tabBytes  = (size_t)NG * NSL * 2 * 4;
    const size_t epOff     = (tabOff + tabBytes + 63) & ~(size_t)63;
    const size_t epBytes   = (size_t)((N + 2) / 3) * 64;
    const size_t needBuck  = tabOff + tabBytes + 64;
    const size_t needPack  = epOff + epBytes + 64;

    const bool okBase = (N <= (1 << 20)) && (nSl <= NSL) && (H <= (1 << 27));
    const bool okPack = okBase && (ws_size >= needPack);
    const bool okBuck = okBase && (ws_size >= needBuck);

    if (okBuck) {
        unsigned int* buck = (unsigned int*)((char*)d_ws + buckOff);
        unsigned int* tab  = (unsigned int*)((char*)d_ws + tabOff);
        int* ep = okPack ? (int*)((char*)d_ws + epOff) : nullptr;

        // out[] is zeroed inside bucket_kernel (per-group) — no memset dispatch.

        hipLaunchKernelGGL(bucket_kernel, dim3(NG), dim3(1024), 0, stream,
                           blocks, offsets, starts, bs, entries, out,
                           buck, tab, ep, H, N, T);

        int gridB = 2048;
        if (gridB > NG * 8) gridB = NG * 8;
        const int gStride = (gridB >= 8) ? (gridB >> 3) : 1;
        const int gpb = (NG + gStride - 1) / gStride;

        if (okPack) {
            hipLaunchKernelGGL(gather_kernel_packed, dim3(gridB), dim3(256), 0, stream,
                               buck, tab, ep, out, H, NG, nSl, gpb);
        } else {
            hipLaunchKernelGGL(gather_kernel, dim3(gridB), dim3(256), 0, stream,
                               buck, tab, entries, out, H, NG, nSl, gpb);
        }
    } else {
        const long total_threads = (long)H * 64;
        const int block = 256;
        const int grid = (int)((total_threads + block - 1) / block);
        hipLaunchKernelGGL(hint_xor_wave, dim3(grid), dim3(block), 0, stream,
                           entries, blocks, offsets, starts, sizes, bs, out, H, N);
    }
}